// Round 1
// baseline (1253.090 us; speedup 1.0000x reference)
//
#include <hip/hip_runtime.h>
#include <math.h>

#define Bq 16
#define Tq 768
#define Cq 768
#define Mq (Bq*Tq)   // 12288

// ---------------------------------------------------------------------------
// Tiled fp32 GEMM:  OUT[m,n] = f( sum_c A[m,c] * W[n,c] )
// A is either the token-shift mix of x (FUSED=true) or a plain buffer.
// BM=BN=128, BK=16, 256 threads, 8x8 micro-tile per thread.
// MODE: 0 = exp(min(.,60))  (k) ; 1 = identity (v) ; 2 = sigmoid (r) ;
//       3 = identity, plain A    (final output GEMM)
// ---------------------------------------------------------------------------
template<int MODE, bool FUSED>
__global__ __launch_bounds__(256)
void gemm_kernel(const float* __restrict__ X,    // x (fused) or rwkv buffer
                 const float* __restrict__ MIX,  // time_mix (fused only)
                 const float* __restrict__ W,    // (C,C) row-major, row = out chan
                 float* __restrict__ OUT)        // (M, C)
{
    __shared__ float As[16][132];   // [k][m], +4 pad keeps rows 16B aligned
    __shared__ float Bs[16][132];   // [k][n]

    const int tid = threadIdx.x;
    const int lr  = tid >> 1;            // 0..127 : row within tile (loader)
    const int lk  = (tid & 1) * 8;       // 0 or 8 : k-offset (loader)
    const int m0  = blockIdx.y * 128;
    const int n0  = blockIdx.x * 128;

    const int ty = tid >> 4;             // 0..15
    const int tx = tid & 15;             // 0..15

    // A row pointers
    const int rg = m0 + lr;              // global row (= b*T + t)
    const int t  = rg % Tq;
    const float* arow = X + (size_t)rg * Cq;
    const float* wrow = W + (size_t)(n0 + lr) * Cq;

    float acc[8][8];
#pragma unroll
    for (int i = 0; i < 8; ++i)
#pragma unroll
        for (int j = 0; j < 8; ++j) acc[i][j] = 0.f;

    for (int kt = 0; kt < Cq / 16; ++kt) {
        const int c0 = kt * 16 + lk;

        // ---- load A fragment (8 floats) ----
        float av[8];
        if (FUSED) {
            const float4 xa = *(const float4*)(arow + c0);
            const float4 xb = *(const float4*)(arow + c0 + 4);
            float4 pa = make_float4(0.f, 0.f, 0.f, 0.f), pb = pa;
            if (t > 0) {
                pa = *(const float4*)(arow - Cq + c0);
                pb = *(const float4*)(arow - Cq + c0 + 4);
            }
            const float4 ma = *(const float4*)(MIX + c0);
            const float4 mb = *(const float4*)(MIX + c0 + 4);
            av[0] = fmaf(ma.x, xa.x - pa.x, pa.x);
            av[1] = fmaf(ma.y, xa.y - pa.y, pa.y);
            av[2] = fmaf(ma.z, xa.z - pa.z, pa.z);
            av[3] = fmaf(ma.w, xa.w - pa.w, pa.w);
            av[4] = fmaf(mb.x, xb.x - pb.x, pb.x);
            av[5] = fmaf(mb.y, xb.y - pb.y, pb.y);
            av[6] = fmaf(mb.z, xb.z - pb.z, pb.z);
            av[7] = fmaf(mb.w, xb.w - pb.w, pb.w);
        } else {
            const float4 xa = *(const float4*)(arow + c0);
            const float4 xb = *(const float4*)(arow + c0 + 4);
            av[0] = xa.x; av[1] = xa.y; av[2] = xa.z; av[3] = xa.w;
            av[4] = xb.x; av[5] = xb.y; av[6] = xb.z; av[7] = xb.w;
        }

        // ---- load W fragment (8 floats) ----
        const float4 wa = *(const float4*)(wrow + c0);
        const float4 wb = *(const float4*)(wrow + c0 + 4);
        float wv[8] = { wa.x, wa.y, wa.z, wa.w, wb.x, wb.y, wb.z, wb.w };

        __syncthreads();   // protect previous iteration's reads
#pragma unroll
        for (int j = 0; j < 8; ++j) {
            As[lk + j][lr] = av[j];
            Bs[lk + j][lr] = wv[j];
        }
        __syncthreads();

        // ---- inner product over this K-tile ----
#pragma unroll
        for (int k = 0; k < 16; ++k) {
            const float4 a0 = *(const float4*)&As[k][ty * 4];
            const float4 a1 = *(const float4*)&As[k][64 + ty * 4];
            const float4 b0 = *(const float4*)&Bs[k][tx * 4];
            const float4 b1 = *(const float4*)&Bs[k][64 + tx * 4];
            const float afr[8] = { a0.x, a0.y, a0.z, a0.w, a1.x, a1.y, a1.z, a1.w };
            const float bfr[8] = { b0.x, b0.y, b0.z, b0.w, b1.x, b1.y, b1.z, b1.w };
#pragma unroll
            for (int i = 0; i < 8; ++i)
#pragma unroll
                for (int j = 0; j < 8; ++j)
                    acc[i][j] = fmaf(afr[i], bfr[j], acc[i][j]);
        }
    }

    // ---- epilogue ----
#pragma unroll
    for (int ih = 0; ih < 2; ++ih) {
#pragma unroll
        for (int i = 0; i < 4; ++i) {
            const int ai = ih * 4 + i;
            const int m  = m0 + ih * 64 + ty * 4 + i;
            float* orow  = OUT + (size_t)m * Cq + n0;
            float vals[8];
#pragma unroll
            for (int j = 0; j < 8; ++j) {
                float v = acc[ai][j];
                if (MODE == 0)      v = expf(fminf(v, 60.f));
                else if (MODE == 2) v = 1.f / (1.f + expf(-v));
                vals[j] = v;
            }
            *(float4*)(orow + tx * 4)      = make_float4(vals[0], vals[1], vals[2], vals[3]);
            *(float4*)(orow + 64 + tx * 4) = make_float4(vals[4], vals[5], vals[6], vals[7]);
        }
    }
}

// ---------------------------------------------------------------------------
// Sequential RWKV scan. One thread per (b, c) column; a block covers 64
// consecutive channels so every per-step load/store is coalesced.
// out may alias kbuf (each element is read then written by the same thread).
// ---------------------------------------------------------------------------
__global__ __launch_bounds__(64)
void scan_kernel(const float* kbuf, const float* vbuf, const float* rbuf,
                 const float* __restrict__ td, const float* __restrict__ tf,
                 float* out)
{
    const int c = blockIdx.x * 64 + threadIdx.x;
    const int b = blockIdx.y;
    const size_t base = ((size_t)b * Tq) * Cq + c;

    const float wd = expf(-expf(td[c]));   // e^{-d}
    const float u  = expf(tf[c]);          // diagonal (time_first) weight

    float a = 0.f, bs = 0.f;
    for (int t = 0; t < Tq; ++t) {
        const size_t idx = base + (size_t)t * Cq;
        const float kt = kbuf[idx];
        const float vt = vbuf[idx];
        const float sr = rbuf[idx];
        const float kv = kt * vt;
        const float num = fmaf(u, kv, a);
        const float den = fmaf(u, kt, bs) + 1e-8f;
        out[idx] = sr * num / den;
        a  = fmaf(wd, a, kv);
        bs = fmaf(wd, bs, kt);
    }
}

extern "C" void kernel_launch(void* const* d_in, const int* in_sizes, int n_in,
                              void* d_out, int out_size, void* d_ws, size_t ws_size,
                              hipStream_t stream)
{
    const float* x  = (const float*)d_in[0];
    const float* td = (const float*)d_in[1];
    const float* tf = (const float*)d_in[2];
    const float* mk = (const float*)d_in[3];
    const float* mv = (const float*)d_in[4];
    const float* mr = (const float*)d_in[5];
    const float* Wk = (const float*)d_in[6];
    const float* Wv = (const float*)d_in[7];
    const float* Wr = (const float*)d_in[8];
    const float* Wo = (const float*)d_in[9];

    float* kbuf = (float*)d_ws;
    float* vbuf = kbuf + (size_t)Mq * Cq;
    float* rbuf = vbuf + (size_t)Mq * Cq;

    const dim3 ggrid(Cq / 128, Mq / 128);   // (6, 96)
    const dim3 gblock(256);

    gemm_kernel<0, true ><<<ggrid, gblock, 0, stream>>>(x, mk, Wk, kbuf);
    gemm_kernel<1, true ><<<ggrid, gblock, 0, stream>>>(x, mv, Wv, vbuf);
    gemm_kernel<2, true ><<<ggrid, gblock, 0, stream>>>(x, mr, Wr, rbuf);

    scan_kernel<<<dim3(Cq / 64, Bq), 64, 0, stream>>>(kbuf, vbuf, rbuf, td, tf, kbuf);

    gemm_kernel<3, false><<<ggrid, gblock, 0, stream>>>(kbuf, nullptr, Wo, (float*)d_out);
}

// Round 2
// 270.018 us; speedup vs baseline: 4.6408x; 4.6408x over previous
//
#include <hip/hip_runtime.h>
#include <math.h>

#define Mq 12288          // B*T
#define Nq 768            // C (output channels)
#define Kq 768            // C (reduce dim)
#define Tq 768
#define Bq 16
#define Cq 768
#define BK 32             // K-tile (bf16 elems) = 64 B = 4 x 16B chunks

typedef __bf16 bf16x8 __attribute__((ext_vector_type(8)));
typedef __bf16 bf16x4 __attribute__((ext_vector_type(4)));
typedef float  floatx4 __attribute__((ext_vector_type(4)));

// async 16B/lane global->LDS (wave-uniform LDS base + lane*16)
#define GLD_LDS16(g, l) __builtin_amdgcn_global_load_lds(                      \
    (const __attribute__((address_space(1))) unsigned int*)(g),                \
    (__attribute__((address_space(3))) unsigned int*)(l), 16, 0, 0)

// ---------------------------------------------------------------------------
// Weight f32 -> bf16 (4 matrices, concatenated into one bf16 pool)
// ---------------------------------------------------------------------------
__global__ __launch_bounds__(256)
void prep_w(const float* __restrict__ Wk, const float* __restrict__ Wv,
            const float* __restrict__ Wr, const float* __restrict__ Wo,
            __bf16* __restrict__ o)
{
    const int i   = blockIdx.x * 256 + threadIdx.x;   // one float4 per thread
    const int a   = i / 147456;                       // which matrix (589824/4)
    const int off = (i - a * 147456) * 4;
    const float* s = (a == 0) ? Wk : (a == 1) ? Wv : (a == 2) ? Wr : Wo;
    const float4 v = *(const float4*)(s + off);
    bf16x4 r = { (__bf16)v.x, (__bf16)v.y, (__bf16)v.z, (__bf16)v.w };
    *(bf16x4*)(o + (size_t)a * 589824 + off) = r;
}

// ---------------------------------------------------------------------------
// Token-shift mix -> bf16 xk, xv, xr
// ---------------------------------------------------------------------------
__global__ __launch_bounds__(256)
void prep_mix(const float* __restrict__ x,
              const float* __restrict__ mk, const float* __restrict__ mv,
              const float* __restrict__ mr,
              __bf16* __restrict__ xk, __bf16* __restrict__ xv,
              __bf16* __restrict__ xr)
{
    const int i  = blockIdx.x * 256 + threadIdx.x;    // one float4 of channels
    const int c4 = i % (Cq / 4);
    const int m  = i / (Cq / 4);
    const int t  = m % Tq;
    const int c0 = c4 * 4;

    const float4 xc = *(const float4*)(x + (size_t)m * Cq + c0);
    float4 xp = make_float4(0.f, 0.f, 0.f, 0.f);
    if (t > 0) xp = *(const float4*)(x + (size_t)(m - 1) * Cq + c0);

    const float4 k4 = *(const float4*)(mk + c0);
    const float4 v4 = *(const float4*)(mv + c0);
    const float4 r4 = *(const float4*)(mr + c0);

    bf16x4 ok = { (__bf16)fmaf(k4.x, xc.x - xp.x, xp.x),
                  (__bf16)fmaf(k4.y, xc.y - xp.y, xp.y),
                  (__bf16)fmaf(k4.z, xc.z - xp.z, xp.z),
                  (__bf16)fmaf(k4.w, xc.w - xp.w, xp.w) };
    bf16x4 ov = { (__bf16)fmaf(v4.x, xc.x - xp.x, xp.x),
                  (__bf16)fmaf(v4.y, xc.y - xp.y, xp.y),
                  (__bf16)fmaf(v4.z, xc.z - xp.z, xp.z),
                  (__bf16)fmaf(v4.w, xc.w - xp.w, xp.w) };
    bf16x4 orr = { (__bf16)fmaf(r4.x, xc.x - xp.x, xp.x),
                   (__bf16)fmaf(r4.y, xc.y - xp.y, xp.y),
                   (__bf16)fmaf(r4.z, xc.z - xp.z, xp.z),
                   (__bf16)fmaf(r4.w, xc.w - xp.w, xp.w) };
    const size_t o = (size_t)m * Cq + c0;
    *(bf16x4*)(xk + o) = ok;
    *(bf16x4*)(xv + o) = ov;
    *(bf16x4*)(xr + o) = orr;
}

// ---------------------------------------------------------------------------
// bf16 MFMA GEMM (NT):  OUT[m,n] = f( sum_k A[m,k] * W[n,k] )
// 128x128 tile, BK=32, 256 threads (4 waves), 4x4 16x16x32 MFMA per wave.
// global_load_lds width-16 staging with XOR-4 chunk swizzle (swizzle applied
// on the global-source side; LDS dest stays wave-uniform-base + lane*16).
// MODE: 0 exp(min(.,60)) ; 1 identity ; 2 sigmoid ; 3 identity (fp32 out)
// ---------------------------------------------------------------------------
template<int MODE, typename OutT>
__global__ __launch_bounds__(256)
void mfma_gemm(const __bf16* __restrict__ A,   // (Mq, Kq)
               const __bf16* __restrict__ W,   // (Nq, Kq)
               OutT* __restrict__ OUT)         // (Mq, Nq)
{
    __shared__ __bf16 As[128 * BK];
    __shared__ __bf16 Bs[128 * BK];

    const int tid  = threadIdx.x;
    const int wave = tid >> 6;
    const int lane = tid & 63;
    const int m0   = blockIdx.y * 128;
    const int n0   = blockIdx.x * 128;

    // ---- staging coords: instr i of wave w covers rows w*32+i*16+(lane>>2)
    const int r0  = wave * 32 + (lane >> 2);          // instr-0 row in tile
    const int kc  = (lane & 3) ^ (r0 & 3);            // swizzled source chunk
    const __bf16* gA0 = A + (size_t)(m0 + r0) * Kq + kc * 8;
    const __bf16* gA1 = gA0 + (size_t)16 * Kq;        // instr-1 row (+16)
    const __bf16* gB0 = W + (size_t)(n0 + r0) * Kq + kc * 8;
    const __bf16* gB1 = gB0 + (size_t)16 * Kq;
    __bf16* lA0 = As + (wave * 2 + 0) * 512;          // 1024 B per instr
    __bf16* lA1 = As + (wave * 2 + 1) * 512;
    __bf16* lB0 = Bs + (wave * 2 + 0) * 512;
    __bf16* lB1 = Bs + (wave * 2 + 1) * 512;

    // ---- reader coords: wave quadrant (qr,qc), 64x64 per wave
    const int qr = wave >> 1, qc = wave & 1;
    const int rowA = qr * 64 + (lane & 15);           // + i*16
    const int rowB = qc * 64 + (lane & 15);           // + j*16
    const int lk   = lane >> 4;                       // logical k chunk 0..3
    const int offA = (lk ^ (rowA & 3)) * 8;           // XOR-4 un-swizzle
    const int offB = (lk ^ (rowB & 3)) * 8;

    floatx4 acc[4][4];
#pragma unroll
    for (int i = 0; i < 4; ++i)
#pragma unroll
        for (int j = 0; j < 4; ++j) acc[i][j] = (floatx4){0.f, 0.f, 0.f, 0.f};

    for (int kt = 0; kt < Kq / BK; ++kt) {
        GLD_LDS16(gA0, lA0);
        GLD_LDS16(gA1, lA1);
        GLD_LDS16(gB0, lB0);
        GLD_LDS16(gB1, lB1);
        gA0 += BK; gA1 += BK; gB0 += BK; gB1 += BK;
        __syncthreads();                    // drains vmcnt(0): tile in LDS

        bf16x8 aF[4], bF[4];
#pragma unroll
        for (int i = 0; i < 4; ++i)
            aF[i] = *(const bf16x8*)(As + (rowA + i * 16) * BK + offA);
#pragma unroll
        for (int j = 0; j < 4; ++j)
            bF[j] = *(const bf16x8*)(Bs + (rowB + j * 16) * BK + offB);

#pragma unroll
        for (int i = 0; i < 4; ++i)
#pragma unroll
            for (int j = 0; j < 4; ++j)
                acc[i][j] = __builtin_amdgcn_mfma_f32_16x16x32_bf16(
                    aF[i], bF[j], acc[i][j], 0, 0, 0);
        __syncthreads();                    // LDS reads done before overwrite
    }

    // ---- epilogue: C/D layout col=lane&15, row=(lane>>4)*4+reg
    const int er = qr * 64 + (lane >> 4) * 4;
    const int ec = qc * 64 + (lane & 15);
#pragma unroll
    for (int i = 0; i < 4; ++i) {
#pragma unroll
        for (int j = 0; j < 4; ++j) {
            const int n = n0 + ec + j * 16;
#pragma unroll
            for (int reg = 0; reg < 4; ++reg) {
                const int m = m0 + er + i * 16 + reg;
                float v = acc[i][j][reg];
                if (MODE == 0)      v = expf(fminf(v, 60.f));
                else if (MODE == 2) v = 1.f / (1.f + expf(-v));
                OUT[(size_t)m * Nq + n] = (OutT)v;
            }
        }
    }
}

// ---------------------------------------------------------------------------
// Segmented RWKV scan: block = 64 channels x 8 segments of 96 steps.
// Phase 1: per-segment local sums (zero init). Phase 2: serial combine of 8
// segment states per channel (wave 0). Phase 3: recompute outputs.
// rwkv (bf16) overwrites rbuf in place.
// ---------------------------------------------------------------------------
#define SEG 8
#define SLEN (Tq / SEG)   // 96

__global__ __launch_bounds__(512)
void scan_kernel(const __bf16* __restrict__ kb, const __bf16* __restrict__ vb,
                 __bf16* rb,
                 const float* __restrict__ td, const float* __restrict__ tf)
{
    __shared__ float aS[SEG][64];
    __shared__ float bS[SEG][64];

    const int cx  = threadIdx.x;          // 0..63
    const int seg = threadIdx.y;          // 0..7
    const int c   = blockIdx.x * 64 + cx;
    const int b   = blockIdx.y;

    const float d  = expf(td[c]);
    const float wd = expf(-d);            // per-step decay
    const float u  = expf(tf[c]);         // diagonal (time_first) weight

    const size_t base = ((size_t)b * Tq + seg * SLEN) * Cq + c;

    // phase 1: local segment sums
    float a = 0.f, bs = 0.f;
    for (int t = 0; t < SLEN; ++t) {
        const size_t idx = base + (size_t)t * Cq;
        const float kt = (float)kb[idx];
        const float vt = (float)vb[idx];
        a  = fmaf(wd, a, kt * vt);
        bs = fmaf(wd, bs, kt);
    }
    aS[seg][cx] = a;
    bS[seg][cx] = bs;
    __syncthreads();

    // phase 2: serial prefix over segments (one wave)
    if (seg == 0) {
        const float w96 = expf(-d * (float)SLEN);   // wd^SLEN exactly
        float ina = 0.f, inb = 0.f;
#pragma unroll
        for (int s = 0; s < SEG; ++s) {
            const float ta = aS[s][cx];
            const float tb = bS[s][cx];
            aS[s][cx] = ina;
            bS[s][cx] = inb;
            ina = fmaf(w96, ina, ta);
            inb = fmaf(w96, inb, tb);
        }
    }
    __syncthreads();

    // phase 3: outputs with incoming state
    a  = aS[seg][cx];
    bs = bS[seg][cx];
    for (int t = 0; t < SLEN; ++t) {
        const size_t idx = base + (size_t)t * Cq;
        const float kt = (float)kb[idx];
        const float vt = (float)vb[idx];
        const float sr = (float)rb[idx];  // sigmoid(r), from GEMM epilogue
        const float kv = kt * vt;
        const float num = fmaf(u, kv, a);
        const float den = fmaf(u, kt, bs) + 1e-8f;
        rb[idx] = (__bf16)(sr * num / den);
        a  = fmaf(wd, a, kv);
        bs = fmaf(wd, bs, kt);
    }
}

extern "C" void kernel_launch(void* const* d_in, const int* in_sizes, int n_in,
                              void* d_out, int out_size, void* d_ws, size_t ws_size,
                              hipStream_t stream)
{
    const float* x  = (const float*)d_in[0];
    const float* td = (const float*)d_in[1];
    const float* tf = (const float*)d_in[2];
    const float* mk = (const float*)d_in[3];
    const float* mv = (const float*)d_in[4];
    const float* mr = (const float*)d_in[5];
    const float* Wk = (const float*)d_in[6];
    const float* Wv = (const float*)d_in[7];
    const float* Wr = (const float*)d_in[8];
    const float* Wo = (const float*)d_in[9];

    const size_t MC = (size_t)Mq * Cq;      // 9,437,184 elems

    // d_out doubles as scratch for xk/xv (2 x bf16 MC = out bytes exactly)
    __bf16* xk = (__bf16*)d_out;
    __bf16* xv = xk + MC;

    // ws: xr | kbuf | vbuf | rbuf(->rwkv) | weights(bf16 x4)  = ~80 MB
    __bf16* xr   = (__bf16*)d_ws;
    __bf16* kbuf = xr + MC;
    __bf16* vbuf = kbuf + MC;
    __bf16* rbuf = vbuf + MC;
    __bf16* Wp   = rbuf + MC;
    __bf16* Wkb = Wp;
    __bf16* Wvb = Wp + 589824;
    __bf16* Wrb = Wp + 2 * 589824;
    __bf16* Wob = Wp + 3 * 589824;

    prep_w<<<2304, 256, 0, stream>>>(Wk, Wv, Wr, Wo, Wp);
    prep_mix<<<(Mq * (Cq / 4)) / 256, 256, 0, stream>>>(x, mk, mv, mr, xk, xv, xr);

    const dim3 ggrid(Nq / 128, Mq / 128);   // (6, 96)
    mfma_gemm<0, __bf16><<<ggrid, 256, 0, stream>>>(xk, Wkb, kbuf);
    mfma_gemm<1, __bf16><<<ggrid, 256, 0, stream>>>(xv, Wvb, vbuf);
    mfma_gemm<2, __bf16><<<ggrid, 256, 0, stream>>>(xr, Wrb, rbuf);

    scan_kernel<<<dim3(Cq / 64, Bq), dim3(64, SEG), 0, stream>>>(
        kbuf, vbuf, rbuf, td, tf);

    mfma_gemm<3, float><<<ggrid, 256, 0, stream>>>(rbuf, Wob, (float*)d_out);
}

// Round 3
// 255.077 us; speedup vs baseline: 4.9126x; 1.0586x over previous
//
#include <hip/hip_runtime.h>
#include <math.h>

#define Mq 12288          // B*T
#define Nq 768            // C (per-matrix output width)
#define Kq 768            // C (reduce dim)
#define Tq 768
#define Bq 16
#define Cq 768
#define BK 64             // K-tile (bf16 elems) = 128 B = 8 x 16B chunks

typedef __bf16 bf16x8 __attribute__((ext_vector_type(8)));
typedef __bf16 bf16x4 __attribute__((ext_vector_type(4)));
typedef float  floatx4 __attribute__((ext_vector_type(4)));

// async 16B/lane global->LDS (LDS operand is wave-uniform base; HW adds lane*16)
#define GLD_LDS16(g, l) __builtin_amdgcn_global_load_lds(                      \
    (const __attribute__((address_space(1))) unsigned int*)(g),                \
    (__attribute__((address_space(3))) unsigned int*)(l), 16, 0, 0)

// ---------------------------------------------------------------------------
// Weight f32 -> bf16 pool: [Wk; Wv; Wr; Wo] rows concatenated -> (3072, 768)
// ---------------------------------------------------------------------------
__global__ __launch_bounds__(256)
void prep_w(const float* __restrict__ Wk, const float* __restrict__ Wv,
            const float* __restrict__ Wr, const float* __restrict__ Wo,
            __bf16* __restrict__ o)
{
    const int i   = blockIdx.x * 256 + threadIdx.x;   // one float4 per thread
    const int a   = i / 147456;                       // which matrix (589824/4)
    const int off = (i - a * 147456) * 4;
    const float* s = (a == 0) ? Wk : (a == 1) ? Wv : (a == 2) ? Wr : Wo;
    const float4 v = *(const float4*)(s + off);
    bf16x4 r = { (__bf16)v.x, (__bf16)v.y, (__bf16)v.z, (__bf16)v.w };
    *(bf16x4*)(o + (size_t)a * 589824 + off) = r;
}

// ---------------------------------------------------------------------------
// Token-shift mix -> bf16 xk, xv, xr
// ---------------------------------------------------------------------------
__global__ __launch_bounds__(256)
void prep_mix(const float* __restrict__ x,
              const float* __restrict__ mk, const float* __restrict__ mv,
              const float* __restrict__ mr,
              __bf16* __restrict__ xk, __bf16* __restrict__ xv,
              __bf16* __restrict__ xr)
{
    const int i  = blockIdx.x * 256 + threadIdx.x;    // one float4 of channels
    const int c4 = i % (Cq / 4);
    const int m  = i / (Cq / 4);
    const int t  = m % Tq;
    const int c0 = c4 * 4;

    const float4 xc = *(const float4*)(x + (size_t)m * Cq + c0);
    float4 xp = make_float4(0.f, 0.f, 0.f, 0.f);
    if (t > 0) xp = *(const float4*)(x + (size_t)(m - 1) * Cq + c0);

    const float4 k4 = *(const float4*)(mk + c0);
    const float4 v4 = *(const float4*)(mv + c0);
    const float4 r4 = *(const float4*)(mr + c0);

    bf16x4 ok = { (__bf16)fmaf(k4.x, xc.x - xp.x, xp.x),
                  (__bf16)fmaf(k4.y, xc.y - xp.y, xp.y),
                  (__bf16)fmaf(k4.z, xc.z - xp.z, xp.z),
                  (__bf16)fmaf(k4.w, xc.w - xp.w, xp.w) };
    bf16x4 ov = { (__bf16)fmaf(v4.x, xc.x - xp.x, xp.x),
                  (__bf16)fmaf(v4.y, xc.y - xp.y, xp.y),
                  (__bf16)fmaf(v4.z, xc.z - xp.z, xp.z),
                  (__bf16)fmaf(v4.w, xc.w - xp.w, xp.w) };
    bf16x4 orr = { (__bf16)fmaf(r4.x, xc.x - xp.x, xp.x),
                   (__bf16)fmaf(r4.y, xc.y - xp.y, xp.y),
                   (__bf16)fmaf(r4.z, xc.z - xp.z, xp.z),
                   (__bf16)fmaf(r4.w, xc.w - xp.w, xp.w) };
    const size_t o = (size_t)m * Cq + c0;
    *(bf16x4*)(xk + o) = ok;
    *(bf16x4*)(xv + o) = ov;
    *(bf16x4*)(xr + o) = orr;
}

// ---------------------------------------------------------------------------
// bf16 MFMA GEMM, 128x128 tile, BK=64, 256 thr, 4x4 16x16x32 MFMA per wave.
// KVR=true : W pool rows 0..2303 (k|v|r), grid.x = 18 strips; strip/6 picks
//            A operand (xk/xv/xr), activation, and output buffer (contiguous
//            kbuf|vbuf|rbuf). All block-uniform.
// KVR=false: plain A, identity, fp32 output (final Wo GEMM), grid.x = 6.
// XOR-8 chunk swizzle applied on the global-source side; LDS dest stays
// wave-uniform-base + lane*16. Read side un-swizzles: 2-way banks = free.
// ---------------------------------------------------------------------------
template<bool KVR>
__global__ __launch_bounds__(256)
void mfma_gemm(const __bf16* __restrict__ A0, const __bf16* __restrict__ A1,
               const __bf16* __restrict__ A2,
               const __bf16* __restrict__ W,     // row = pool out-channel
               __bf16* __restrict__ OUTb,        // KVR: kbuf (3 mats contig)
               float*  __restrict__ OUTf)        // !KVR: d_out
{
    __shared__ __bf16 As[128 * BK];   // 16 KB, rows of 128 B
    __shared__ __bf16 Bs[128 * BK];   // 16 KB

    const int tid   = threadIdx.x;
    const int wave  = tid >> 6;
    const int lane  = tid & 63;
    const int m0    = blockIdx.y * 128;
    const int nb    = blockIdx.x;
    const int matid = KVR ? nb / 6 : 0;
    const int n0    = KVR ? (nb % 6) * 128 : nb * 128;  // col in out matrix
    const int wn0   = nb * 128;                         // row in W pool

    const __bf16* A = KVR ? (matid == 0 ? A0 : matid == 1 ? A1 : A2) : A0;

    // ---- staging coords: instr i of wave w covers rows (w*4+i)*8 .. +7
    const int r8 = lane >> 3;            // row within 8-row group
    const int cc = lane & 7;             // dest chunk within 128-B row
    const int sc = cc ^ r8;              // XOR-8 swizzled source chunk
    const __bf16* gA[4];
    const __bf16* gB[4];
    __bf16* lA[4];
    __bf16* lB[4];
#pragma unroll
    for (int i = 0; i < 4; ++i) {
        const int row = (wave * 4 + i) * 8 + r8;
        gA[i] = A + (size_t)(m0  + row) * Kq + sc * 8;
        gB[i] = W + (size_t)(wn0 + row) * Kq + sc * 8;
        lA[i] = As + (wave * 4 + i) * 512;     // 1 KB per instr
        lB[i] = Bs + (wave * 4 + i) * 512;
    }

    // ---- reader coords: wave quadrant (qr,qc), 64x64 per wave
    const int qr = wave >> 1, qc = wave & 1;
    const int rowA = qr * 64 + (lane & 15);    // + i*16
    const int rowB = qc * 64 + (lane & 15);    // + j*16
    const int lk   = lane >> 4;                // logical 16B chunk 0..3 (per K=32)

    floatx4 acc[4][4];
#pragma unroll
    for (int i = 0; i < 4; ++i)
#pragma unroll
        for (int j = 0; j < 4; ++j) acc[i][j] = (floatx4){0.f, 0.f, 0.f, 0.f};

    for (int kt = 0; kt < Kq / BK; ++kt) {
#pragma unroll
        for (int i = 0; i < 4; ++i) {
            GLD_LDS16(gA[i], lA[i]);
            GLD_LDS16(gB[i], lB[i]);
            gA[i] += BK; gB[i] += BK;
        }
        __syncthreads();                 // drains vmcnt(0): tile in LDS

#pragma unroll
        for (int kk = 0; kk < 2; ++kk) { // two K=32 steps per BK=64 tile
            bf16x8 aF[4], bF[4];
#pragma unroll
            for (int i = 0; i < 4; ++i) {
                const int ra = rowA + i * 16;
                aF[i] = *(const bf16x8*)(As + ra * BK +
                                         (((kk << 2) | lk) ^ (ra & 7)) * 8);
            }
#pragma unroll
            for (int j = 0; j < 4; ++j) {
                const int rb = rowB + j * 16;
                bF[j] = *(const bf16x8*)(Bs + rb * BK +
                                         (((kk << 2) | lk) ^ (rb & 7)) * 8);
            }
#pragma unroll
            for (int i = 0; i < 4; ++i)
#pragma unroll
                for (int j = 0; j < 4; ++j)
                    acc[i][j] = __builtin_amdgcn_mfma_f32_16x16x32_bf16(
                        aF[i], bF[j], acc[i][j], 0, 0, 0);
        }
        __syncthreads();                 // LDS reads done before overwrite
    }

    // ---- epilogue: C/D layout col=lane&15, row=(lane>>4)*4+reg
    const int er = qr * 64 + (lane >> 4) * 4;
    const int ec = qc * 64 + (lane & 15);
#pragma unroll
    for (int i = 0; i < 4; ++i) {
#pragma unroll
        for (int j = 0; j < 4; ++j) {
            const int n = n0 + ec + j * 16;
#pragma unroll
            for (int reg = 0; reg < 4; ++reg) {
                const int m = m0 + er + i * 16 + reg;
                float v = acc[i][j][reg];
                if (KVR) {
                    if (matid == 0)      v = expf(fminf(v, 60.f));
                    else if (matid == 2) v = 1.f / (1.f + expf(-v));
                    OUTb[(size_t)matid * Mq * Nq + (size_t)m * Nq + n] = (__bf16)v;
                } else {
                    OUTf[(size_t)m * Nq + n] = v;
                }
            }
        }
    }
}

// ---------------------------------------------------------------------------
// Segmented RWKV scan: block = 64 channels x 8 segments of 96 steps.
// ---------------------------------------------------------------------------
#define SEG 8
#define SLEN (Tq / SEG)   // 96

__global__ __launch_bounds__(512)
void scan_kernel(const __bf16* __restrict__ kb, const __bf16* __restrict__ vb,
                 __bf16* rb,
                 const float* __restrict__ td, const float* __restrict__ tf)
{
    __shared__ float aS[SEG][64];
    __shared__ float bS[SEG][64];

    const int cx  = threadIdx.x;          // 0..63
    const int seg = threadIdx.y;          // 0..7
    const int c   = blockIdx.x * 64 + cx;
    const int b   = blockIdx.y;

    const float d  = expf(td[c]);
    const float wd = expf(-d);            // per-step decay
    const float u  = expf(tf[c]);         // diagonal (time_first) weight

    const size_t base = ((size_t)b * Tq + seg * SLEN) * Cq + c;

    // phase 1: local segment sums
    float a = 0.f, bs = 0.f;
    for (int t = 0; t < SLEN; ++t) {
        const size_t idx = base + (size_t)t * Cq;
        const float kt = (float)kb[idx];
        const float vt = (float)vb[idx];
        a  = fmaf(wd, a, kt * vt);
        bs = fmaf(wd, bs, kt);
    }
    aS[seg][cx] = a;
    bS[seg][cx] = bs;
    __syncthreads();

    // phase 2: serial prefix over segments (one wave)
    if (seg == 0) {
        const float w96 = expf(-d * (float)SLEN);   // wd^SLEN exactly
        float ina = 0.f, inb = 0.f;
#pragma unroll
        for (int s = 0; s < SEG; ++s) {
            const float ta = aS[s][cx];
            const float tb = bS[s][cx];
            aS[s][cx] = ina;
            bS[s][cx] = inb;
            ina = fmaf(w96, ina, ta);
            inb = fmaf(w96, inb, tb);
        }
    }
    __syncthreads();

    // phase 3: outputs with incoming state
    a  = aS[seg][cx];
    bs = bS[seg][cx];
    for (int t = 0; t < SLEN; ++t) {
        const size_t idx = base + (size_t)t * Cq;
        const float kt = (float)kb[idx];
        const float vt = (float)vb[idx];
        const float sr = (float)rb[idx];  // sigmoid(r), from GEMM epilogue
        const float kv = kt * vt;
        const float num = fmaf(u, kv, a);
        const float den = fmaf(u, kt, bs) + 1e-8f;
        rb[idx] = (__bf16)(sr * num / den);
        a  = fmaf(wd, a, kv);
        bs = fmaf(wd, bs, kt);
    }
}

extern "C" void kernel_launch(void* const* d_in, const int* in_sizes, int n_in,
                              void* d_out, int out_size, void* d_ws, size_t ws_size,
                              hipStream_t stream)
{
    const float* x  = (const float*)d_in[0];
    const float* td = (const float*)d_in[1];
    const float* tf = (const float*)d_in[2];
    const float* mk = (const float*)d_in[3];
    const float* mv = (const float*)d_in[4];
    const float* mr = (const float*)d_in[5];
    const float* Wk = (const float*)d_in[6];
    const float* Wv = (const float*)d_in[7];
    const float* Wr = (const float*)d_in[8];
    const float* Wo = (const float*)d_in[9];

    const size_t MC = (size_t)Mq * Cq;      // 9,437,184 elems

    // d_out doubles as scratch for xk/xv (2 x bf16 MC = out bytes exactly)
    __bf16* xk = (__bf16*)d_out;
    __bf16* xv = xk + MC;

    // ws: xr | kbuf | vbuf | rbuf(->rwkv) | weights(bf16 x4)  = ~80 MB
    __bf16* xr   = (__bf16*)d_ws;
    __bf16* kbuf = xr + MC;                 // kbuf,vbuf,rbuf contiguous!
    __bf16* vbuf = kbuf + MC;
    __bf16* rbuf = vbuf + MC;
    __bf16* Wp   = rbuf + MC;
    __bf16* Wob  = Wp + 3 * 589824;

    prep_w<<<2304, 256, 0, stream>>>(Wk, Wv, Wr, Wo, Wp);
    prep_mix<<<(Mq * (Cq / 4)) / 256, 256, 0, stream>>>(x, mk, mv, mr, xk, xv, xr);

    // fused k|v|r GEMM: 18 n-strips x 96 m-tiles = 1728 blocks
    mfma_gemm<true><<<dim3(18, 96), 256, 0, stream>>>(
        xk, xv, xr, Wp, kbuf, nullptr);

    scan_kernel<<<dim3(Cq / 64, Bq), dim3(64, SEG), 0, stream>>>(
        kbuf, vbuf, rbuf, td, tf);

    mfma_gemm<false><<<dim3(6, 96), 256, 0, stream>>>(
        rbuf, nullptr, nullptr, Wob, nullptr, (float*)d_out);
}

// Round 4
// 243.625 us; speedup vs baseline: 5.1435x; 1.0470x over previous
//
#include <hip/hip_runtime.h>
#include <math.h>

#define Mq 12288          // B*T
#define Nq 768            // C (per-matrix output width)
#define Kq 768            // C (reduce dim)
#define Tq 768
#define Bq 16
#define Cq 768
#define BK 64             // K-tile (bf16) = 128 B = 8 x 16B chunks
#define BM 64             // M-tile (tokens)

typedef __bf16 bf16x8 __attribute__((ext_vector_type(8)));
typedef __bf16 bf16x4 __attribute__((ext_vector_type(4)));
typedef __bf16 bf16x2 __attribute__((ext_vector_type(2)));
typedef float  floatx4 __attribute__((ext_vector_type(4)));

// async 16B/lane global->LDS (LDS operand is wave-uniform base; HW adds lane*16)
#define GLD_LDS16(g, l) __builtin_amdgcn_global_load_lds(                      \
    (const __attribute__((address_space(1))) unsigned int*)(g),                \
    (__attribute__((address_space(3))) unsigned int*)(l), 16, 0, 0)

// ---------------------------------------------------------------------------
// Fused prep: blocks [0,9216) token-shift mix -> bf16 xk/xv/xr;
//             blocks [9216,11520) weight f32 -> bf16 pool (k|v|r|o rows).
// ---------------------------------------------------------------------------
__global__ __launch_bounds__(256)
void prep_kernel(const float* __restrict__ x,
                 const float* __restrict__ mk, const float* __restrict__ mv,
                 const float* __restrict__ mr,
                 const float* __restrict__ Wk, const float* __restrict__ Wv,
                 const float* __restrict__ Wr, const float* __restrict__ Wo,
                 __bf16* __restrict__ xk, __bf16* __restrict__ xv,
                 __bf16* __restrict__ xr, __bf16* __restrict__ wp)
{
    const int bid = blockIdx.x;
    if (bid < 9216) {
        const int i  = bid * 256 + threadIdx.x;       // one float4 of channels
        const int c4 = i % (Cq / 4);
        const int m  = i / (Cq / 4);
        const int t  = m % Tq;
        const int c0 = c4 * 4;

        const float4 xc = *(const float4*)(x + (size_t)m * Cq + c0);
        float4 xp = make_float4(0.f, 0.f, 0.f, 0.f);
        if (t > 0) xp = *(const float4*)(x + (size_t)(m - 1) * Cq + c0);

        const float4 k4 = *(const float4*)(mk + c0);
        const float4 v4 = *(const float4*)(mv + c0);
        const float4 r4 = *(const float4*)(mr + c0);

        bf16x4 ok = { (__bf16)fmaf(k4.x, xc.x - xp.x, xp.x),
                      (__bf16)fmaf(k4.y, xc.y - xp.y, xp.y),
                      (__bf16)fmaf(k4.z, xc.z - xp.z, xp.z),
                      (__bf16)fmaf(k4.w, xc.w - xp.w, xp.w) };
        bf16x4 ov = { (__bf16)fmaf(v4.x, xc.x - xp.x, xp.x),
                      (__bf16)fmaf(v4.y, xc.y - xp.y, xp.y),
                      (__bf16)fmaf(v4.z, xc.z - xp.z, xp.z),
                      (__bf16)fmaf(v4.w, xc.w - xp.w, xp.w) };
        bf16x4 orr = { (__bf16)fmaf(r4.x, xc.x - xp.x, xp.x),
                       (__bf16)fmaf(r4.y, xc.y - xp.y, xp.y),
                       (__bf16)fmaf(r4.z, xc.z - xp.z, xp.z),
                       (__bf16)fmaf(r4.w, xc.w - xp.w, xp.w) };
        const size_t o = (size_t)m * Cq + c0;
        *(bf16x4*)(xk + o) = ok;
        *(bf16x4*)(xv + o) = ov;
        *(bf16x4*)(xr + o) = orr;
    } else {
        const int i   = (bid - 9216) * 256 + threadIdx.x; // one float4
        const int a   = i / 147456;                       // which matrix
        const int off = (i - a * 147456) * 4;
        const float* s = (a == 0) ? Wk : (a == 1) ? Wv : (a == 2) ? Wr : Wo;
        const float4 v = *(const float4*)(s + off);
        bf16x4 r = { (__bf16)v.x, (__bf16)v.y, (__bf16)v.z, (__bf16)v.w };
        *(bf16x4*)(wp + (size_t)a * 589824 + off) = r;
    }
}

// ---------------------------------------------------------------------------
// bf16 MFMA GEMM, 64x128 tile (BMxBN), BK=64, 256 thr.
// Operand-swapped: W-fragment is the MFMA A operand, so D's register dim is
// 4 consecutive OUTPUT CHANNELS -> vectorized bf16x4/float4 stores.
// Wave quadrants: qm=wave&1 (32 tokens), qn=wave>>1 (64 channels);
// per wave per kk: 4 (ch) x 2 (tok) MFMA tiles; acc = 8 x floatx4 = 32 VGPR.
// KVR=true : W pool rows 0..2303 (k|v|r); grid.x=18; strip/6 -> A operand,
//            activation, output buffer (kbuf|vbuf|rbuf contiguous).
// KVR=false: plain A, identity, fp32 out, grid.x=6.
// XOR-8 chunk swizzle on global-source side; LDS dest stays uniform+lane*16.
// ---------------------------------------------------------------------------
template<bool KVR>
__global__ __launch_bounds__(256, 6)
void mfma_gemm(const __bf16* __restrict__ A0, const __bf16* __restrict__ A1,
               const __bf16* __restrict__ A2,
               const __bf16* __restrict__ W,
               __bf16* __restrict__ OUTb, float* __restrict__ OUTf)
{
    __shared__ __bf16 As[BM * BK];    //  8 KB (tokens)
    __shared__ __bf16 Bs[128 * BK];   // 16 KB (channels)

    const int tid   = threadIdx.x;
    const int wave  = tid >> 6;
    const int lane  = tid & 63;
    const int m0    = blockIdx.y * BM;
    const int nb    = blockIdx.x;
    const int matid = KVR ? nb / 6 : 0;
    const int n0    = KVR ? (nb % 6) * 128 : nb * 128;
    const int wn0   = nb * 128;

    const __bf16* A = KVR ? (matid == 0 ? A0 : matid == 1 ? A1 : A2) : A0;

    // ---- staging: 1024 B per global_load_lds instr = 8 rows of 128 B
    const int r8 = lane >> 3;             // row within 8-row group
    const int sc = (lane & 7) ^ r8;       // XOR-8 swizzled source chunk
    const __bf16* gA[2];  __bf16* lA[2];
    const __bf16* gB[4];  __bf16* lB[4];
#pragma unroll
    for (int i = 0; i < 2; ++i) {
        const int row = (wave * 2 + i) * 8 + r8;
        gA[i] = A + (size_t)(m0 + row) * Kq + sc * 8;
        lA[i] = As + (wave * 2 + i) * 512;
    }
#pragma unroll
    for (int i = 0; i < 4; ++i) {
        const int row = (wave * 4 + i) * 8 + r8;
        gB[i] = W + (size_t)(wn0 + row) * Kq + sc * 8;
        lB[i] = Bs + (wave * 4 + i) * 512;
    }

    // ---- reader coords
    const int qm = wave & 1;              // token half (32)
    const int qn = wave >> 1;             // channel half (64)
    const int xRow = qm * 32 + (lane & 15);   // + j*16, in As
    const int wRow = qn * 64 + (lane & 15);   // + i*16, in Bs
    const int lk   = lane >> 4;               // logical 16B chunk within K=32

    floatx4 acc[4][2];
#pragma unroll
    for (int i = 0; i < 4; ++i)
#pragma unroll
        for (int j = 0; j < 2; ++j) acc[i][j] = (floatx4){0.f, 0.f, 0.f, 0.f};

    for (int kt = 0; kt < Kq / BK; ++kt) {
#pragma unroll
        for (int i = 0; i < 2; ++i) { GLD_LDS16(gA[i], lA[i]); gA[i] += BK; }
#pragma unroll
        for (int i = 0; i < 4; ++i) { GLD_LDS16(gB[i], lB[i]); gB[i] += BK; }
        __syncthreads();                  // drains vmcnt(0): tile in LDS

#pragma unroll
        for (int kk = 0; kk < 2; ++kk) {
            bf16x8 wF[4], xF[2];
#pragma unroll
            for (int i = 0; i < 4; ++i) {
                const int r = wRow + i * 16;
                wF[i] = *(const bf16x8*)(Bs + r * BK +
                                         (((kk << 2) | lk) ^ (r & 7)) * 8);
            }
#pragma unroll
            for (int j = 0; j < 2; ++j) {
                const int r = xRow + j * 16;
                xF[j] = *(const bf16x8*)(As + r * BK +
                                         (((kk << 2) | lk) ^ (r & 7)) * 8);
            }
#pragma unroll
            for (int i = 0; i < 4; ++i)
#pragma unroll
                for (int j = 0; j < 2; ++j)
                    acc[i][j] = __builtin_amdgcn_mfma_f32_16x16x32_bf16(
                        wF[i], xF[j], acc[i][j], 0, 0, 0);
        }
        __syncthreads();                  // LDS reads done before overwrite
    }

    // ---- epilogue: D col = token (lane&15), row-reg = 4 consecutive channels
#pragma unroll
    for (int j = 0; j < 2; ++j) {
        const int tok = m0 + qm * 32 + j * 16 + (lane & 15);
#pragma unroll
        for (int i = 0; i < 4; ++i) {
            const int ch = n0 + qn * 64 + i * 16 + (lane >> 4) * 4;
            if (KVR) {
                float v0 = acc[i][j][0], v1 = acc[i][j][1];
                float v2 = acc[i][j][2], v3 = acc[i][j][3];
                if (matid == 0) {
                    v0 = expf(fminf(v0, 60.f)); v1 = expf(fminf(v1, 60.f));
                    v2 = expf(fminf(v2, 60.f)); v3 = expf(fminf(v3, 60.f));
                } else if (matid == 2) {
                    v0 = 1.f / (1.f + expf(-v0)); v1 = 1.f / (1.f + expf(-v1));
                    v2 = 1.f / (1.f + expf(-v2)); v3 = 1.f / (1.f + expf(-v3));
                }
                bf16x4 o = { (__bf16)v0, (__bf16)v1, (__bf16)v2, (__bf16)v3 };
                *(bf16x4*)(OUTb + (size_t)matid * Mq * Nq +
                           (size_t)tok * Nq + ch) = o;
            } else {
                floatx4 o = acc[i][j];
                *(floatx4*)(OUTf + (size_t)tok * Nq + ch) = o;
            }
        }
    }
}

// ---------------------------------------------------------------------------
// Segmented RWKV scan: block = 64 lanes x 2 channels x 16 segments of 48.
// ---------------------------------------------------------------------------
#define SEG 16
#define SLEN (Tq / SEG)   // 48

__global__ __launch_bounds__(1024)
void scan_kernel(const __bf16* __restrict__ kb, const __bf16* __restrict__ vb,
                 __bf16* rb,
                 const float* __restrict__ td, const float* __restrict__ tf)
{
    __shared__ float2 aS[SEG][64];
    __shared__ float2 bS[SEG][64];

    const int cx  = threadIdx.x;          // 0..63 -> channel pair
    const int seg = threadIdx.y;          // 0..15
    const int c0  = blockIdx.x * 128 + cx * 2;
    const int b   = blockIdx.y;

    const float d0 = expf(td[c0]),     d1 = expf(td[c0 + 1]);
    const float w0 = expf(-d0),        w1 = expf(-d1);      // per-step decay
    const float u0 = expf(tf[c0]),     u1 = expf(tf[c0 + 1]);

    const size_t base = ((size_t)b * Tq + seg * SLEN) * Cq + c0;

    // phase 1: local segment sums (zero init)
    float a0 = 0.f, a1 = 0.f, s0 = 0.f, s1 = 0.f;
#pragma unroll 4
    for (int t = 0; t < SLEN; ++t) {
        const size_t idx = base + (size_t)t * Cq;
        const bf16x2 k2 = *(const bf16x2*)(kb + idx);
        const bf16x2 v2 = *(const bf16x2*)(vb + idx);
        const float k0 = (float)k2[0], k1 = (float)k2[1];
        a0 = fmaf(w0, a0, k0 * (float)v2[0]);
        a1 = fmaf(w1, a1, k1 * (float)v2[1]);
        s0 = fmaf(w0, s0, k0);
        s1 = fmaf(w1, s1, k1);
    }
    aS[seg][cx] = make_float2(a0, a1);
    bS[seg][cx] = make_float2(s0, s1);
    __syncthreads();

    // phase 2: serial prefix over segments (first row of threads)
    if (seg == 0) {
        const float W0 = expf(-d0 * (float)SLEN);   // w0^SLEN
        const float W1 = expf(-d1 * (float)SLEN);
        float ia0 = 0.f, ia1 = 0.f, ib0 = 0.f, ib1 = 0.f;
#pragma unroll
        for (int s = 0; s < SEG; ++s) {
            const float2 ta = aS[s][cx];
            const float2 tb = bS[s][cx];
            aS[s][cx] = make_float2(ia0, ia1);
            bS[s][cx] = make_float2(ib0, ib1);
            ia0 = fmaf(W0, ia0, ta.x);  ia1 = fmaf(W1, ia1, ta.y);
            ib0 = fmaf(W0, ib0, tb.x);  ib1 = fmaf(W1, ib1, tb.y);
        }
    }
    __syncthreads();

    // phase 3: outputs with incoming state
    const float2 ain = aS[seg][cx];
    const float2 bin = bS[seg][cx];
    a0 = ain.x; a1 = ain.y; s0 = bin.x; s1 = bin.y;
#pragma unroll 2
    for (int t = 0; t < SLEN; ++t) {
        const size_t idx = base + (size_t)t * Cq;
        const bf16x2 k2 = *(const bf16x2*)(kb + idx);
        const bf16x2 v2 = *(const bf16x2*)(vb + idx);
        const bf16x2 r2 = *(const bf16x2*)(rb + idx);   // sigmoid(r)
        const float k0 = (float)k2[0], k1 = (float)k2[1];
        const float kv0 = k0 * (float)v2[0], kv1 = k1 * (float)v2[1];
        const float n0 = fmaf(u0, kv0, a0), n1 = fmaf(u1, kv1, a1);
        const float e0 = fmaf(u0, k0, s0) + 1e-8f;
        const float e1 = fmaf(u1, k1, s1) + 1e-8f;
        bf16x2 o = { (__bf16)((float)r2[0] * n0 / e0),
                     (__bf16)((float)r2[1] * n1 / e1) };
        *(bf16x2*)(rb + idx) = o;
        a0 = fmaf(w0, a0, kv0);  a1 = fmaf(w1, a1, kv1);
        s0 = fmaf(w0, s0, k0);   s1 = fmaf(w1, s1, k1);
    }
}

extern "C" void kernel_launch(void* const* d_in, const int* in_sizes, int n_in,
                              void* d_out, int out_size, void* d_ws, size_t ws_size,
                              hipStream_t stream)
{
    const float* x  = (const float*)d_in[0];
    const float* td = (const float*)d_in[1];
    const float* tf = (const float*)d_in[2];
    const float* mk = (const float*)d_in[3];
    const float* mv = (const float*)d_in[4];
    const float* mr = (const float*)d_in[5];
    const float* Wk = (const float*)d_in[6];
    const float* Wv = (const float*)d_in[7];
    const float* Wr = (const float*)d_in[8];
    const float* Wo = (const float*)d_in[9];

    const size_t MC = (size_t)Mq * Cq;      // 9,437,184 elems

    // d_out doubles as scratch for xk/xv (2 x bf16 MC = out bytes exactly)
    __bf16* xk = (__bf16*)d_out;
    __bf16* xv = xk + MC;

    // ws: xr | kbuf | vbuf | rbuf(->rwkv) | weights(bf16 x4)  = ~80 MB
    __bf16* xr   = (__bf16*)d_ws;
    __bf16* kbuf = xr + MC;                 // kbuf,vbuf,rbuf contiguous
    __bf16* vbuf = kbuf + MC;
    __bf16* rbuf = vbuf + MC;
    __bf16* Wp   = rbuf + MC;
    __bf16* Wob  = Wp + 3 * 589824;

    prep_kernel<<<11520, 256, 0, stream>>>(x, mk, mv, mr, Wk, Wv, Wr, Wo,
                                           xk, xv, xr, Wp);

    // fused k|v|r GEMM: 18 n-strips x 192 m-tiles = 3456 blocks
    mfma_gemm<true><<<dim3(18, Mq / BM), 256, 0, stream>>>(
        xk, xv, xr, Wp, kbuf, nullptr);

    scan_kernel<<<dim3(Cq / 128, Bq), dim3(64, SEG), 0, stream>>>(
        kbuf, vbuf, rbuf, td, tf);

    mfma_gemm<false><<<dim3(6, Mq / BM), 256, 0, stream>>>(
        rbuf, nullptr, nullptr, Wob, nullptr, (float*)d_out);
}

// Round 5
// 233.036 us; speedup vs baseline: 5.3772x; 1.0454x over previous
//
#include <hip/hip_runtime.h>
#include <math.h>

#define Mq 12288          // B*T
#define Nq 768            // C (per-matrix output width)
#define Kq 768            // C (reduce dim)
#define Tq 768
#define Bq 16
#define Cq 768
#define BK 64             // K-tile (bf16) = 128 B = 8 x 16B chunks
#define BM 64             // M-tile (tokens)

typedef __bf16 bf16x8 __attribute__((ext_vector_type(8)));
typedef __bf16 bf16x4 __attribute__((ext_vector_type(4)));
typedef __bf16 bf16x2 __attribute__((ext_vector_type(2)));
typedef float  floatx4 __attribute__((ext_vector_type(4)));

// async 16B/lane global->LDS (LDS operand is wave-uniform base; HW adds lane*16)
#define GLD_LDS16(g, l) __builtin_amdgcn_global_load_lds(                      \
    (const __attribute__((address_space(1))) unsigned int*)(g),                \
    (__attribute__((address_space(3))) unsigned int*)(l), 16, 0, 0)

// ---------------------------------------------------------------------------
// Fused prep: blocks [0,9216) token-shift mix -> bf16 xk/xv/xr;
//             blocks [9216,11520) weight f32 -> bf16 pool (k|v|r|o rows).
// ---------------------------------------------------------------------------
__global__ __launch_bounds__(256)
void prep_kernel(const float* __restrict__ x,
                 const float* __restrict__ mk, const float* __restrict__ mv,
                 const float* __restrict__ mr,
                 const float* __restrict__ Wk, const float* __restrict__ Wv,
                 const float* __restrict__ Wr, const float* __restrict__ Wo,
                 __bf16* __restrict__ xk, __bf16* __restrict__ xv,
                 __bf16* __restrict__ xr, __bf16* __restrict__ wp)
{
    const int bid = blockIdx.x;
    if (bid < 9216) {
        const int i  = bid * 256 + threadIdx.x;       // one float4 of channels
        const int c4 = i % (Cq / 4);
        const int m  = i / (Cq / 4);
        const int t  = m % Tq;
        const int c0 = c4 * 4;

        const float4 xc = *(const float4*)(x + (size_t)m * Cq + c0);
        float4 xp = make_float4(0.f, 0.f, 0.f, 0.f);
        if (t > 0) xp = *(const float4*)(x + (size_t)(m - 1) * Cq + c0);

        const float4 k4 = *(const float4*)(mk + c0);
        const float4 v4 = *(const float4*)(mv + c0);
        const float4 r4 = *(const float4*)(mr + c0);

        bf16x4 ok = { (__bf16)fmaf(k4.x, xc.x - xp.x, xp.x),
                      (__bf16)fmaf(k4.y, xc.y - xp.y, xp.y),
                      (__bf16)fmaf(k4.z, xc.z - xp.z, xp.z),
                      (__bf16)fmaf(k4.w, xc.w - xp.w, xp.w) };
        bf16x4 ov = { (__bf16)fmaf(v4.x, xc.x - xp.x, xp.x),
                      (__bf16)fmaf(v4.y, xc.y - xp.y, xp.y),
                      (__bf16)fmaf(v4.z, xc.z - xp.z, xp.z),
                      (__bf16)fmaf(v4.w, xc.w - xp.w, xp.w) };
        bf16x4 orr = { (__bf16)fmaf(r4.x, xc.x - xp.x, xp.x),
                       (__bf16)fmaf(r4.y, xc.y - xp.y, xp.y),
                       (__bf16)fmaf(r4.z, xc.z - xp.z, xp.z),
                       (__bf16)fmaf(r4.w, xc.w - xp.w, xp.w) };
        const size_t o = (size_t)m * Cq + c0;
        *(bf16x4*)(xk + o) = ok;
        *(bf16x4*)(xv + o) = ov;
        *(bf16x4*)(xr + o) = orr;
    } else {
        const int i   = (bid - 9216) * 256 + threadIdx.x; // one float4
        const int a   = i / 147456;                       // which matrix
        const int off = (i - a * 147456) * 4;
        const float* s = (a == 0) ? Wk : (a == 1) ? Wv : (a == 2) ? Wr : Wo;
        const float4 v = *(const float4*)(s + off);
        bf16x4 r = { (__bf16)v.x, (__bf16)v.y, (__bf16)v.z, (__bf16)v.w };
        *(bf16x4*)(wp + (size_t)a * 589824 + off) = r;
    }
}

// ---------------------------------------------------------------------------
// bf16 MFMA GEMM, 64x128 tile, BK=64, 256 thr, operand-swapped (W = MFMA A).
// 1-D grid with XCD-aware swizzle: xcd = blockIdx&7 owns m-tiles
// [xcd*24, xcd*24+24), strip-fastest within -> per-XCD L2 working set =
// all B strips (KVR: 3.5 MB) + current A tiles (~0.3 MB), < 4 MB L2.
// STRIPS = 18 (KVR: k|v|r x 6 n-tiles) or 6 (final Wo GEMM).
// ---------------------------------------------------------------------------
template<bool KVR>
__global__ __launch_bounds__(256, 6)
void mfma_gemm(const __bf16* __restrict__ A0, const __bf16* __restrict__ A1,
               const __bf16* __restrict__ A2,
               const __bf16* __restrict__ W,
               __bf16* __restrict__ OUTb, float* __restrict__ OUTf)
{
    __shared__ __bf16 As[BM * BK];    //  8 KB (tokens)
    __shared__ __bf16 Bs[128 * BK];   // 16 KB (channels)

    const int STRIPS = KVR ? 18 : 6;

    // ---- XCD-aware block swizzle (8 XCDs, 192 m-tiles = 8 x 24)
    const int i_    = blockIdx.x;
    const int xcd   = i_ & 7;
    const int j_    = i_ >> 3;
    const int strip = j_ % STRIPS;
    const int mt    = xcd * 24 + j_ / STRIPS;

    const int tid   = threadIdx.x;
    const int wave  = tid >> 6;
    const int lane  = tid & 63;
    const int m0    = mt * BM;
    const int matid = KVR ? strip / 6 : 0;
    const int n0    = KVR ? (strip % 6) * 128 : strip * 128;
    const int wn0   = strip * 128;

    const __bf16* A = KVR ? (matid == 0 ? A0 : matid == 1 ? A1 : A2) : A0;

    // ---- staging: 1024 B per global_load_lds instr = 8 rows of 128 B
    const int r8 = lane >> 3;             // row within 8-row group
    const int sc = (lane & 7) ^ r8;       // XOR-8 swizzled source chunk
    const __bf16* gA[2];  __bf16* lA[2];
    const __bf16* gB[4];  __bf16* lB[4];
#pragma unroll
    for (int i = 0; i < 2; ++i) {
        const int row = (wave * 2 + i) * 8 + r8;
        gA[i] = A + (size_t)(m0 + row) * Kq + sc * 8;
        lA[i] = As + (wave * 2 + i) * 512;
    }
#pragma unroll
    for (int i = 0; i < 4; ++i) {
        const int row = (wave * 4 + i) * 8 + r8;
        gB[i] = W + (size_t)(wn0 + row) * Kq + sc * 8;
        lB[i] = Bs + (wave * 4 + i) * 512;
    }

    // ---- reader coords
    const int qm = wave & 1;              // token half (32)
    const int qn = wave >> 1;             // channel half (64)
    const int xRow = qm * 32 + (lane & 15);   // + j*16, in As
    const int wRow = qn * 64 + (lane & 15);   // + i*16, in Bs
    const int lk   = lane >> 4;               // logical 16B chunk within K=32

    floatx4 acc[4][2];
#pragma unroll
    for (int i = 0; i < 4; ++i)
#pragma unroll
        for (int j = 0; j < 2; ++j) acc[i][j] = (floatx4){0.f, 0.f, 0.f, 0.f};

    for (int kt = 0; kt < Kq / BK; ++kt) {
#pragma unroll
        for (int i = 0; i < 2; ++i) { GLD_LDS16(gA[i], lA[i]); gA[i] += BK; }
#pragma unroll
        for (int i = 0; i < 4; ++i) { GLD_LDS16(gB[i], lB[i]); gB[i] += BK; }
        __syncthreads();                  // drains vmcnt(0): tile in LDS

#pragma unroll
        for (int kk = 0; kk < 2; ++kk) {
            bf16x8 wF[4], xF[2];
#pragma unroll
            for (int i = 0; i < 4; ++i) {
                const int r = wRow + i * 16;
                wF[i] = *(const bf16x8*)(Bs + r * BK +
                                         (((kk << 2) | lk) ^ (r & 7)) * 8);
            }
#pragma unroll
            for (int j = 0; j < 2; ++j) {
                const int r = xRow + j * 16;
                xF[j] = *(const bf16x8*)(As + r * BK +
                                         (((kk << 2) | lk) ^ (r & 7)) * 8);
            }
#pragma unroll
            for (int i = 0; i < 4; ++i)
#pragma unroll
                for (int j = 0; j < 2; ++j)
                    acc[i][j] = __builtin_amdgcn_mfma_f32_16x16x32_bf16(
                        wF[i], xF[j], acc[i][j], 0, 0, 0);
        }
        __syncthreads();                  // LDS reads done before overwrite
    }

    // ---- epilogue: D col = token (lane&15), row-reg = 4 consecutive channels
#pragma unroll
    for (int j = 0; j < 2; ++j) {
        const int tok = m0 + qm * 32 + j * 16 + (lane & 15);
#pragma unroll
        for (int i = 0; i < 4; ++i) {
            const int ch = n0 + qn * 64 + i * 16 + (lane >> 4) * 4;
            if (KVR) {
                float v0 = acc[i][j][0], v1 = acc[i][j][1];
                float v2 = acc[i][j][2], v3 = acc[i][j][3];
                if (matid == 0) {
                    v0 = expf(fminf(v0, 60.f)); v1 = expf(fminf(v1, 60.f));
                    v2 = expf(fminf(v2, 60.f)); v3 = expf(fminf(v3, 60.f));
                } else if (matid == 2) {
                    v0 = 1.f / (1.f + expf(-v0)); v1 = 1.f / (1.f + expf(-v1));
                    v2 = 1.f / (1.f + expf(-v2)); v3 = 1.f / (1.f + expf(-v3));
                }
                bf16x4 o = { (__bf16)v0, (__bf16)v1, (__bf16)v2, (__bf16)v3 };
                *(bf16x4*)(OUTb + (size_t)matid * Mq * Nq +
                           (size_t)tok * Nq + ch) = o;
            } else {
                floatx4 o = acc[i][j];
                *(floatx4*)(OUTf + (size_t)tok * Nq + ch) = o;
            }
        }
    }
}

// ---------------------------------------------------------------------------
// Segmented RWKV scan: block = 64 lanes x 2 channels x 16 segments of 48.
// ---------------------------------------------------------------------------
#define SEG 16
#define SLEN (Tq / SEG)   // 48

__global__ __launch_bounds__(1024)
void scan_kernel(const __bf16* __restrict__ kb, const __bf16* __restrict__ vb,
                 __bf16* rb,
                 const float* __restrict__ td, const float* __restrict__ tf)
{
    __shared__ float2 aS[SEG][64];
    __shared__ float2 bS[SEG][64];

    const int cx  = threadIdx.x;          // 0..63 -> channel pair
    const int seg = threadIdx.y;          // 0..15
    const int c0  = blockIdx.x * 128 + cx * 2;
    const int b   = blockIdx.y;

    const float d0 = expf(td[c0]),     d1 = expf(td[c0 + 1]);
    const float w0 = expf(-d0),        w1 = expf(-d1);      // per-step decay
    const float u0 = expf(tf[c0]),     u1 = expf(tf[c0 + 1]);

    const size_t base = ((size_t)b * Tq + seg * SLEN) * Cq + c0;

    // phase 1: local segment sums (zero init)
    float a0 = 0.f, a1 = 0.f, s0 = 0.f, s1 = 0.f;
#pragma unroll 4
    for (int t = 0; t < SLEN; ++t) {
        const size_t idx = base + (size_t)t * Cq;
        const bf16x2 k2 = *(const bf16x2*)(kb + idx);
        const bf16x2 v2 = *(const bf16x2*)(vb + idx);
        const float k0 = (float)k2[0], k1 = (float)k2[1];
        a0 = fmaf(w0, a0, k0 * (float)v2[0]);
        a1 = fmaf(w1, a1, k1 * (float)v2[1]);
        s0 = fmaf(w0, s0, k0);
        s1 = fmaf(w1, s1, k1);
    }
    aS[seg][cx] = make_float2(a0, a1);
    bS[seg][cx] = make_float2(s0, s1);
    __syncthreads();

    // phase 2: serial prefix over segments (first row of threads)
    if (seg == 0) {
        const float W0 = expf(-d0 * (float)SLEN);   // w0^SLEN
        const float W1 = expf(-d1 * (float)SLEN);
        float ia0 = 0.f, ia1 = 0.f, ib0 = 0.f, ib1 = 0.f;
#pragma unroll
        for (int s = 0; s < SEG; ++s) {
            const float2 ta = aS[s][cx];
            const float2 tb = bS[s][cx];
            aS[s][cx] = make_float2(ia0, ia1);
            bS[s][cx] = make_float2(ib0, ib1);
            ia0 = fmaf(W0, ia0, ta.x);  ia1 = fmaf(W1, ia1, ta.y);
            ib0 = fmaf(W0, ib0, tb.x);  ib1 = fmaf(W1, ib1, tb.y);
        }
    }
    __syncthreads();

    // phase 3: outputs with incoming state
    const float2 ain = aS[seg][cx];
    const float2 bin = bS[seg][cx];
    a0 = ain.x; a1 = ain.y; s0 = bin.x; s1 = bin.y;
#pragma unroll 2
    for (int t = 0; t < SLEN; ++t) {
        const size_t idx = base + (size_t)t * Cq;
        const bf16x2 k2 = *(const bf16x2*)(kb + idx);
        const bf16x2 v2 = *(const bf16x2*)(vb + idx);
        const bf16x2 r2 = *(const bf16x2*)(rb + idx);   // sigmoid(r)
        const float k0 = (float)k2[0], k1 = (float)k2[1];
        const float kv0 = k0 * (float)v2[0], kv1 = k1 * (float)v2[1];
        const float n0 = fmaf(u0, kv0, a0), n1 = fmaf(u1, kv1, a1);
        const float e0 = fmaf(u0, k0, s0) + 1e-8f;
        const float e1 = fmaf(u1, k1, s1) + 1e-8f;
        bf16x2 o = { (__bf16)((float)r2[0] * n0 / e0),
                     (__bf16)((float)r2[1] * n1 / e1) };
        *(bf16x2*)(rb + idx) = o;
        a0 = fmaf(w0, a0, kv0);  a1 = fmaf(w1, a1, kv1);
        s0 = fmaf(w0, s0, k0);   s1 = fmaf(w1, s1, k1);
    }
}

extern "C" void kernel_launch(void* const* d_in, const int* in_sizes, int n_in,
                              void* d_out, int out_size, void* d_ws, size_t ws_size,
                              hipStream_t stream)
{
    const float* x  = (const float*)d_in[0];
    const float* td = (const float*)d_in[1];
    const float* tf = (const float*)d_in[2];
    const float* mk = (const float*)d_in[3];
    const float* mv = (const float*)d_in[4];
    const float* mr = (const float*)d_in[5];
    const float* Wk = (const float*)d_in[6];
    const float* Wv = (const float*)d_in[7];
    const float* Wr = (const float*)d_in[8];
    const float* Wo = (const float*)d_in[9];

    const size_t MC = (size_t)Mq * Cq;      // 9,437,184 elems

    // d_out doubles as scratch for xk/xv (2 x bf16 MC = out bytes exactly)
    __bf16* xk = (__bf16*)d_out;
    __bf16* xv = xk + MC;

    // ws: xr | kbuf | vbuf | rbuf(->rwkv) | weights(bf16 x4)  = ~80 MB
    __bf16* xr   = (__bf16*)d_ws;
    __bf16* kbuf = xr + MC;                 // kbuf,vbuf,rbuf contiguous
    __bf16* vbuf = kbuf + MC;
    __bf16* rbuf = vbuf + MC;
    __bf16* Wp   = rbuf + MC;
    __bf16* Wob  = Wp + 3 * 589824;

    prep_kernel<<<11520, 256, 0, stream>>>(x, mk, mv, mr, Wk, Wv, Wr, Wo,
                                           xk, xv, xr, Wp);

    // fused k|v|r GEMM: 18 strips x 192 m-tiles, XCD-swizzled 1-D grid
    mfma_gemm<true><<<18 * 192, 256, 0, stream>>>(
        xk, xv, xr, Wp, kbuf, nullptr);

    scan_kernel<<<dim3(Cq / 128, Bq), dim3(64, SEG), 0, stream>>>(
        kbuf, vbuf, rbuf, td, tf);

    mfma_gemm<false><<<6 * 192, 256, 0, stream>>>(
        rbuf, nullptr, nullptr, Wob, nullptr, (float*)d_out);
}